// Round 11
// baseline (6816.571 us; speedup 1.0000x reference)
//
#include <hip/hip_runtime.h>

// ---------------- problem constants ----------------
constexpr int N_ = 1024;   // ITEM_SIZE
constexpr int B_ = 64;     // BATCH
constexpr int T_ = 64;     // SEQ
constexpr int CAP = 128;   // max in-degree cap (mean ~33, max ~60)
constexpr size_t OUT0 = (size_t)B_ * T_ * N_;   // outs f32, then h f32

// ---------------- workspace layout (float offsets) — total ~13.9 MB ----------------
constexpr size_t WINTo  = 0;        // w_in^T  [j][i] 128*64 = 8192
constexpr size_t WOUTTo = 8192;     // w_out^T                 8192
constexpr size_t WIHTo  = 16384;    // w_ih^T  [j][g]  64*96 = 6144
constexpr size_t WHHo   = 22528;    // w_hh row-major          3072
constexpr size_t WFCo   = 25600;    // 32
constexpr size_t BINo   = 25632;    // 64
constexpr size_t BOUTo  = 25696;    // 64
constexpr size_t BIHo   = 25760;    // 96
constexpr size_t BHHo   = 25856;    // 96
constexpr size_t BFCo   = 25952;    // 16 (1 used)
constexpr size_t INAo   = 25968;    // 1024
constexpr size_t OUTAo  = 26992;    // 1024
constexpr size_t CCNTo  = 28016;    // 1024 int
constexpr size_t DTFo   = 29040;    // 16 (dtype flag int)
constexpr size_t IEMo   = 29056;    // item_emb f32 32768
constexpr size_t REMo   = 61824;    // resp_emb f32 65536
constexpr size_t SUMEMBo= 127360;   // sum item_emb over in-neighbors: 1024*32
constexpr size_t OMASKo = 160128;   // u64[1024][16] out-neighbor bitmask (32768 f-slots)
constexpr size_t CIDXo  = 192896;   // 1024*128 int (CSC col lists, ascending)
constexpr size_t GIBo   = 323968;   // gi cache bf16 [b][n][96] = 6,291,456 ushort
// end = 3,469,696 floats ≈ 13.9 MB

// ---------------- LDS layout (dynamic, float offsets) ----------------
constexpr int LDSF_H   = 0;         // h [1024][32] f32 = 32768
constexpr int LDSF_FEA = 32768;     // fea_stage [12][192] f32 = 2304
constexpr int LDSF_DL  = 35072;     // dlist 128 ints
constexpr int LDS_FLOATS = 35200;
constexpr int LDS_BYTES  = LDS_FLOATS * 4;   // 140,800 B -> 1 block/CU, 12 waves

// ---------------- helpers ----------------
__device__ __forceinline__ float bf2f(unsigned short u) {
    union { unsigned int i; float f; } x; x.i = ((unsigned int)u) << 16; return x.f;
}
__device__ __forceinline__ unsigned short f2bf(float f) {
    union { float f; unsigned int u; } x; x.f = f;
    unsigned int u = x.u;
    return (unsigned short)((u + 0x7fffu + ((u >> 16) & 1u)) >> 16);  // RNE
}
__device__ __forceinline__ float sigm(float x) { return 1.f / (1.f + __expf(-x)); }
__device__ __forceinline__ float tanhx(float x) {
    x = fminf(15.f, fmaxf(-15.f, x));
    float e = __expf(2.f * x);
    return (e - 1.f) / (e + 1.f);
}
__device__ __forceinline__ float ldg_any(const void* p, int i, int isbf) {
    return isbf ? bf2f(((const unsigned short*)p)[i]) : ((const float*)p)[i];
}

// ---------------- prep: detect input float dtype from adj bit patterns ----------------
__global__ void k_detect(const unsigned int* __restrict__ adjw, float* __restrict__ ws)
{
    __shared__ int f;
    if (threadIdx.x == 0) f = 0;
    __syncthreads();
    int local = 0;
    for (int i = threadIdx.x; i < 524288; i += blockDim.x) {
        unsigned int w = adjw[i];
        if ((w & 0xFFFFu) == 0x3F80u) local = 1;
    }
    if (local) atomicOr(&f, 1);
    __syncthreads();
    if (threadIdx.x == 0) ((int*)(ws + DTFo))[0] = f;
}

// ---------------- prep: convert/pack weights -> f32 ----------------
__global__ void k_convert(const void* __restrict__ w_in,  const void* __restrict__ b_in,
                          const void* __restrict__ w_out, const void* __restrict__ b_out,
                          const void* __restrict__ in_a,  const void* __restrict__ out_a,
                          const void* __restrict__ w_ih,  const void* __restrict__ w_hh,
                          const void* __restrict__ b_ih,  const void* __restrict__ b_hh,
                          const void* __restrict__ w_fc,  const void* __restrict__ b_fc,
                          const void* __restrict__ item_emb, const void* __restrict__ resp_emb,
                          float* __restrict__ ws)
{
    const int isbf = ((const int*)(ws + DTFo))[0];
    const int tg  = blockIdx.x * blockDim.x + threadIdx.x;
    const int tot = gridDim.x * blockDim.x;
    for (int f = tg; f < 8192; f += tot) {
        int i = f & 63, j = f >> 6;
        ws[WINTo + f]  = ldg_any(w_in , i * 128 + j, isbf);
        ws[WOUTTo + f] = ldg_any(w_out, i * 128 + j, isbf);
    }
    for (int f = tg; f < 6144; f += tot) {
        int g = f % 96, j = f / 96;
        ws[WIHTo + f] = ldg_any(w_ih, g * 64 + j, isbf);
    }
    for (int f = tg; f < 3072; f += tot) ws[WHHo + f] = ldg_any(w_hh, f, isbf);
    for (int f = tg; f < 32;   f += tot) ws[WFCo + f] = ldg_any(w_fc, f, isbf);
    for (int f = tg; f < 64;   f += tot) { ws[BINo + f] = ldg_any(b_in, f, isbf); ws[BOUTo + f] = ldg_any(b_out, f, isbf); }
    for (int f = tg; f < 96;   f += tot) { ws[BIHo + f] = ldg_any(b_ih, f, isbf); ws[BHHo + f] = ldg_any(b_hh, f, isbf); }
    if (tg == 0) ws[BFCo] = ldg_any(b_fc, 0, isbf);
    for (int f = tg; f < 1024; f += tot) { ws[INAo + f] = ldg_any(in_a, f, isbf); ws[OUTAo + f] = ldg_any(out_a, f, isbf); }
    for (int f = tg; f < 32768; f += tot) ws[IEMo + f] = ldg_any(item_emb, f, isbf);
    for (int f = tg; f < 65536; f += tot) ws[REMo + f] = ldg_any(resp_emb, f, isbf);
}

// ---------------- prep: build CSC adjacency (in-neighbor lists) ----------------
__global__ void k_csc(const void* __restrict__ adj, float* __restrict__ ws)
{
    const int isbf = ((const int*)(ws + DTFo))[0];
    const int v = blockIdx.x;
    const int lane = threadIdx.x;
    int* ccnt = (int*)(ws + CCNTo);
    int* cidx = (int*)(ws + CIDXo);
    int cnt = 0;
    for (int ch = 0; ch < 16; ++ch) {
        int row = ch * 64 + lane;
        bool nz;
        if (isbf) nz = (((const unsigned short*)adj)[row * 1024 + v] != 0);
        else      nz = (((const float*)adj)[row * 1024 + v] != 0.f);
        unsigned long long m = __ballot(nz);
        int pos = cnt + __popcll(m & ((1ull << lane) - 1ull));
        if (nz && pos < CAP) cidx[v * CAP + pos] = row;
        cnt += __popcll(m);
    }
    if (lane == 0) ccnt[v] = (cnt > CAP) ? CAP : cnt;
}

// ---------------- prep: out-neighbor bitmasks + static embedding sums ----------------
__global__ void k_emb(const void* __restrict__ adj, float* __restrict__ ws)
{
    const int isbf = ((const int*)(ws + DTFo))[0];
    const int v = blockIdx.x;
    const int lane = threadIdx.x;
    unsigned long long* om = (unsigned long long*)(ws + OMASKo);
    for (int w = 0; w < 16; ++w) {
        int col = w * 64 + lane;
        bool nz;
        if (isbf) nz = (((const unsigned short*)adj)[v * 1024 + col] != 0);
        else      nz = (((const float*)adj)[v * 1024 + col] != 0.f);
        unsigned long long m = __ballot(nz);
        if (lane == 0) om[v * 16 + w] = m;
    }
    const int cnt = ((const int*)(ws + CCNTo))[v];
    const int* cl = (const int*)(ws + CIDXo) + v * CAP;
    float acc = 0.f;
    for (int k = 0; k < cnt; ++k) {
        int u = cl[k];
        if (lane < 32) acc += ws[IEMo + u * 32 + lane];
    }
    if (lane < 32) ws[SUMEMBo + v * 32 + lane] = acc;
}

// ---------------- prep: gi(bf16) = b_ih (ws re-poisoned each launch) ----------------
__global__ void k_init(float* __restrict__ ws)
{
    const size_t tg  = (size_t)blockIdx.x * blockDim.x + threadIdx.x;
    const size_t tot = (size_t)gridDim.x * blockDim.x;
    const float* bih = ws + BIHo;
    unsigned short* gib = (unsigned short*)(ws + GIBo);
    for (size_t i = tg; i < 6291456u; i += tot) {
        int g = (int)(i % 96);            // [b][n][g]
        gib[i] = f2bf(bih[g]);
    }
}

// ---------------- main: 64 blocks (1/batch) x 768 threads; ZERO cross-block sync ----------------
// 12 waves -> 3 waves/SIMD -> VGPR cap ~170: register-stationary w_hh survives
// (round-10 failure: 1024 thr -> cap 128 -> compiler chose 64 -> spill -> 805 MB fetch).
__global__ __launch_bounds__(768, 3) void gkt_main(
    const int* __restrict__ item_ids, const int* __restrict__ responses,
    float* ws, float* __restrict__ out)
{
    extern __shared__ float smem[];
    float* h_lds = smem + LDSF_H;                 // [1024][32]
    float* fea_stage = smem + LDSF_FEA;           // [12][192]
    int* dlist = (int*)(smem + LDSF_DL);          // [128]

    const int tid  = threadIdx.x;
    const int lane = tid & 63;
    const int wave = tid >> 6;          // 0..11
    const int b    = blockIdx.x;        // batch
    const int s    = lane & 31;
    const int gsel = (lane >> 5) & 1;
    const int group= wave * 2 + gsel;   // 0..23, owns nodes {group + 24k}

    unsigned short* GIb = (unsigned short*)(ws + GIBo) + (size_t)b * 98304;  // [n][96] bf16
    const float* __restrict__ winT  = ws + WINTo;
    const float* __restrict__ woutT = ws + WOUTTo;
    const float* __restrict__ wihT  = ws + WIHTo;
    const float* __restrict__ whh   = ws + WHHo;
    const float* __restrict__ bin_f = ws + BINo;
    const float* __restrict__ bout_f= ws + BOUTo;
    const float* __restrict__ bih_f = ws + BIHo;
    const float* __restrict__ bhh_f = ws + BHHo;
    const float* __restrict__ ina_f = ws + INAo;
    const float* __restrict__ outa_f= ws + OUTAo;
    const float* __restrict__ iem   = ws + IEMo;
    const float* __restrict__ rem   = ws + REMo;
    const float* __restrict__ semb  = ws + SUMEMBo;
    const int* __restrict__ ccnt = (const int*)(ws + CCNTo);
    const int* __restrict__ cidx = (const int*)(ws + CIDXo);
    const unsigned long long* __restrict__ omk = (const unsigned long long*)(ws + OMASKo);

    // init h = 0
    for (int i = tid; i < 32768; i += 768) h_lds[i] = 0.f;

    // register-stationary GRU recurrent weights for this lane's state index s
    float wr[32], wz[32], wn[32];
    #pragma unroll
    for (int j = 0; j < 32; ++j) {
        wr[j] = whh[s * 32 + j];
        wz[j] = whh[(32 + s) * 32 + j];
        wn[j] = whh[(64 + s) * 32 + j];
    }
    const float bhr = bhh_f[s], bhz = bhh_f[32 + s], bhn = bhh_f[64 + s];
    const float wfcs = ws[WFCo + s];
    const float bfc  = ws[BFCo];
    __syncthreads();

    for (int t = 0; t < T_; ++t) {
        const int item = item_ids[b * T_ + t];
        const int resp = responses[b * T_ + t];
        const int ndst = ccnt[item];
        if (tid < ndst) dlist[tid] = cidx[item * CAP + tid];
        __syncthreads();
        const float remv = (lane >= 32) ? rem[resp * 32 + (lane - 32)] : 0.f;

        // ---- phase A: one wave per dst node (i stride 12); full-wave h-agg ----
        float* fstage = fea_stage + wave * 192;
        for (int i = wave; i < ndst; i += 12) {
            const int v = dlist[i];
            const int cv = ccnt[v];
            const int* cl = cidx + v * CAP;
            float ph = 0.f;
            for (int k = gsel; k < cv; k += 2) {
                const int u = cl[k];
                ph += h_lds[u * 32 + s];
            }
            ph += __shfl_xor(ph, 32);
            float own, agg;
            if (lane < 32) {
                own = h_lds[v * 32 + lane];
                agg = ph;
            } else {
                const int j = lane - 32;
                own = (v == item) ? remv : iem[v * 32 + j];
                const bool hasit = (omk[item * 16 + (v >> 6)] >> (v & 63)) & 1ull;
                agg = semb[v * 32 + j] + (hasit ? (remv - iem[item * 32 + j]) : 0.f);
            }
            fstage[lane]      = own;
            fstage[64 + lane] = agg;
            float ain = 0.f, aout = 0.f;
            const float4* f4p = (const float4*)fstage;
            #pragma unroll 8
            for (int c = 0; c < 32; ++c) {
                const float4 f = f4p[c];
                ain  += f.x * winT [(4*c+0)*64 + lane] + f.y * winT [(4*c+1)*64 + lane]
                      + f.z * winT [(4*c+2)*64 + lane] + f.w * winT [(4*c+3)*64 + lane];
                aout += f.x * woutT[(4*c+0)*64 + lane] + f.y * woutT[(4*c+1)*64 + lane]
                      + f.z * woutT[(4*c+2)*64 + lane] + f.w * woutT[(4*c+3)*64 + lane];
            }
            ain  += bin_f[lane];
            aout += bout_f[lane];
            const float dstv = outa_f[v] * aout + ina_f[v] * ain;
            fstage[128 + lane] = dstv;
            float g0 = bih_f[lane];
            float g1 = (lane < 32) ? bih_f[64 + lane] : 0.f;
            const float4* d4p = (const float4*)(fstage + 128);
            #pragma unroll 8
            for (int c = 0; c < 16; ++c) {
                const float4 dv = d4p[c];
                g0 += dv.x * wihT[(4*c+0)*96 + lane] + dv.y * wihT[(4*c+1)*96 + lane]
                    + dv.z * wihT[(4*c+2)*96 + lane] + dv.w * wihT[(4*c+3)*96 + lane];
                if (lane < 32) {
                    g1 += dv.x * wihT[(4*c+0)*96 + 64 + lane] + dv.y * wihT[(4*c+1)*96 + 64 + lane]
                        + dv.z * wihT[(4*c+2)*96 + 64 + lane] + dv.w * wihT[(4*c+3)*96 + 64 + lane];
                }
            }
            unsigned short* grow = GIb + (size_t)v * 96;
            grow[lane] = f2bf(g0);
            if (lane < 32) grow[64 + lane] = f2bf(g1);
        }
        __syncthreads();   // gi (global, same-CU L1) + h reads done

        // ---- phase B: GRU; group owns nodes {group+24k}; gi ring-1 prefetch ----
        {
            int nl = group;
            const unsigned short* gp = GIb + (size_t)nl * 96;
            unsigned short cS = gp[s], c32 = gp[32 + s], c64 = gp[64 + s];
            while (nl < 1024) {
                const int nn = nl + 24;
                unsigned short nS = 0, n32 = 0, n64 = 0;
                if (nn < 1024) {
                    const unsigned short* gn = GIb + (size_t)nn * 96;
                    nS = gn[s]; n32 = gn[32 + s]; n64 = gn[64 + s];
                }
                const float4* hrow = (const float4*)(h_lds + nl * 32);
                float4 ch[8];
                #pragma unroll
                for (int q = 0; q < 8; ++q) ch[q] = hrow[q];
                const float h_own = h_lds[nl * 32 + s];
                float ar = bhr, az = bhz, an = bhn;
                const float* hf = (const float*)ch;
                #pragma unroll
                for (int j = 0; j < 32; ++j) {
                    const float hv = hf[j];
                    ar += wr[j] * hv; az += wz[j] * hv; an += wn[j] * hv;
                }
                const float gir = bf2f(cS), giz = bf2f(c32), gin = bf2f(c64);
                const float rg = sigm(gir + ar);
                const float zg = sigm(giz + az);
                const float ng = tanhx(gin + rg * an);
                const float hv2 = (1.f - zg) * ng + zg * h_own;
                h_lds[nl * 32 + s] = hv2;
                float red = hv2 * wfcs;
                red += __shfl_xor(red, 16); red += __shfl_xor(red, 8);
                red += __shfl_xor(red, 4);  red += __shfl_xor(red, 2);
                red += __shfl_xor(red, 1);
                if (s == 0) out[(size_t)b * 65536 + (size_t)t * 1024 + nl] = sigm(red + bfc);
                if (t == T_ - 1) out[OUT0 + (size_t)b * 32768 + (size_t)nl * 32 + s] = hv2;
                cS = nS; c32 = n32; c64 = n64;
                nl = nn;
            }
        }
        __syncthreads();   // h writes visible before next step's phase A
    }
}

extern "C" void kernel_launch(void* const* d_in, const int* in_sizes, int n_in,
                              void* d_out, int out_size, void* d_ws, size_t ws_size,
                              hipStream_t stream)
{
    (void)in_sizes; (void)n_in; (void)out_size; (void)ws_size;
    const int* item_ids  = (const int*)d_in[0];
    const int* responses = (const int*)d_in[1];
    const void* adj      = d_in[2];
    const void* item_emb = d_in[3];
    const void* resp_emb = d_in[4];
    const void* w_in  = d_in[5];
    const void* b_in  = d_in[6];
    const void* w_out = d_in[7];
    const void* b_out = d_in[8];
    const void* in_a  = d_in[9];
    const void* out_a = d_in[10];
    const void* w_ih  = d_in[11];
    const void* w_hh  = d_in[12];
    const void* b_ih  = d_in[13];
    const void* b_hh  = d_in[14];
    const void* w_fc  = d_in[15];
    const void* b_fc  = d_in[16];
    float* ws = (float*)d_ws;
    float* out = (float*)d_out;

    (void)hipFuncSetAttribute((const void*)gkt_main,
                              hipFuncAttributeMaxDynamicSharedMemorySize, LDS_BYTES);

    k_detect<<<dim3(1), dim3(1024), 0, stream>>>((const unsigned int*)adj, ws);
    k_convert<<<dim3(64), dim3(256), 0, stream>>>(w_in, b_in, w_out, b_out, in_a, out_a,
                                                  w_ih, w_hh, b_ih, b_hh, w_fc, b_fc,
                                                  item_emb, resp_emb, ws);
    k_csc<<<dim3(1024), dim3(64), 0, stream>>>(adj, ws);
    k_emb<<<dim3(1024), dim3(64), 0, stream>>>(adj, ws);
    k_init<<<dim3(512), dim3(256), 0, stream>>>(ws);

    gkt_main<<<dim3(64), dim3(768), LDS_BYTES, stream>>>(item_ids, responses, ws, out);
}

// Round 12
// 2949.644 us; speedup vs baseline: 2.3110x; 2.3110x over previous
//
#include <hip/hip_runtime.h>

// ---------------- problem constants ----------------
constexpr int N_ = 1024;   // ITEM_SIZE
constexpr int B_ = 64;     // BATCH
constexpr int T_ = 64;     // SEQ
constexpr int CAP = 128;   // max in-degree cap (mean ~33, max ~60)
constexpr size_t OUT0 = (size_t)B_ * T_ * N_;   // 4,194,304 f32 (outs), then B*N*S h (f32)

// ---------------- workspace layout (float offsets) — total ~9.7 MB ----------------
constexpr size_t WINTo  = 0;        // w_in^T  [j][i] 128*64 = 8192
constexpr size_t WOUTTo = 8192;     // w_out^T                 8192
constexpr size_t WIHTo  = 16384;    // w_ih^T  [j][g]  64*96 = 6144
constexpr size_t WHHo   = 22528;    // w_hh row-major          3072
constexpr size_t WFCo   = 25600;    // 32
constexpr size_t BINo   = 25632;    // 64
constexpr size_t BOUTo  = 25696;    // 64
constexpr size_t BIHo   = 25760;    // 96
constexpr size_t BHHo   = 25856;    // 96
constexpr size_t BFCo   = 25952;    // 16 (1 used)
constexpr size_t INAo   = 25968;    // 1024
constexpr size_t OUTAo  = 26992;    // 1024
constexpr size_t CCNTo  = 28016;    // 1024 int (in-degree per node)
constexpr size_t DTFo   = 29040;    // 16 (dtype flag int)
constexpr size_t IEMo   = 29056;    // item_emb f32 32768
constexpr size_t REMo   = 61824;    // resp_emb f32 65536
constexpr size_t SUMEMBo= 127360;   // sum of item_emb over in-neighbors: 1024*32
constexpr size_t QCNTo  = 160128;   // 1024*4 ints: counts of cidx[v] entries < 256/512/768
constexpr size_t OMASKo = 164224;   // u64[1024][16]: omask[v] bit j = adj[v][j]  (32768 f slots)
constexpr size_t CIDXo  = 196992;   // 1024*128 int (CSC col lists, ascending)
constexpr size_t PARTo  = 328064;   // partial h-sums f32 [par2][b64][i128][sub4*32+lane32] = 2,097,152
constexpr size_t BARo   = 2425216;  // 64 ints: per-batch epoch barrier counters
// end = 2,425,280 floats ≈ 9.7 MB

// ---------------- LDS layout (dynamic, float offsets) ----------------
constexpr int LDSF_H   = 0;         // h block-range [256][32] f32 = 8192
constexpr int LDSF_GI  = 8192;      // gi [256][96] bf16 = 24576 ushort = 12288 f-slots
constexpr int LDSF_FEA = 20480;     // fea_stage [8][192] f32 = 1536
constexpr int LDSF_DL  = 22016;     // dlist 128 ints
constexpr int LDS_FLOATS = 22144;
constexpr int LDS_BYTES  = LDS_FLOATS * 4;   // 88,576 B -> 1 block/CU

// ---------------- helpers ----------------
__device__ __forceinline__ float bf2f(unsigned short u) {
    union { unsigned int i; float f; } x; x.i = ((unsigned int)u) << 16; return x.f;
}
__device__ __forceinline__ unsigned short f2bf(float f) {
    union { float f; unsigned int u; } x; x.f = f;
    unsigned int u = x.u;
    return (unsigned short)((u + 0x7fffu + ((u >> 16) & 1u)) >> 16);  // RNE
}
__device__ __forceinline__ float sigm(float x) { return 1.f / (1.f + __expf(-x)); }
__device__ __forceinline__ float tanhx(float x) {
    x = fminf(15.f, fmaxf(-15.f, x));
    float e = __expf(2.f * x);
    return (e - 1.f) / (e + 1.f);
}
__device__ __forceinline__ float ldg_any(const void* p, int i, int isbf) {
    return isbf ? bf2f(((const unsigned short*)p)[i]) : ((const float*)p)[i];
}

// 4-block per-batch epoch barrier.
// ROUND-12 CHANGE: poll with RELAXED atomic loads (no per-poll L2 invalidate — the
// acquire-spin in rounds 8-9 emitted buffer_inv every iteration, evicting the chip-wide
// weight working set and costing ~45us/step). One acquire after exit + periodic
// acquire safety-valve. Leading __syncthreads drains all waves' stores (round-8 fix).
__device__ __forceinline__ void bar4(int* c, int& ep, int tid) {
    __syncthreads();
    if (tid == 0) {
        __hip_atomic_fetch_add(c, 1, __ATOMIC_RELEASE, __HIP_MEMORY_SCOPE_AGENT);
        const int target = 4 * (++ep);
        int spins = 0;
        while (__hip_atomic_load(c, __ATOMIC_RELAXED, __HIP_MEMORY_SCOPE_AGENT) < target) {
            __builtin_amdgcn_s_sleep(1);
            if (((++spins) & 255) == 0)
                (void)__hip_atomic_load(c, __ATOMIC_ACQUIRE, __HIP_MEMORY_SCOPE_AGENT);
        }
        (void)__hip_atomic_load(c, __ATOMIC_ACQUIRE, __HIP_MEMORY_SCOPE_AGENT);
    } else {
        ++ep;
    }
    __syncthreads();
}

// ---------------- prep: detect input float dtype from adj bit patterns ----------------
__global__ void k_detect(const unsigned int* __restrict__ adjw, float* __restrict__ ws)
{
    __shared__ int f;
    if (threadIdx.x == 0) f = 0;
    __syncthreads();
    int local = 0;
    for (int i = threadIdx.x; i < 524288; i += blockDim.x) {
        unsigned int w = adjw[i];
        if ((w & 0xFFFFu) == 0x3F80u) local = 1;
    }
    if (local) atomicOr(&f, 1);
    __syncthreads();
    if (threadIdx.x == 0) ((int*)(ws + DTFo))[0] = f;
}

// ---------------- prep: convert/pack weights -> f32 ----------------
__global__ void k_convert(const void* __restrict__ w_in,  const void* __restrict__ b_in,
                          const void* __restrict__ w_out, const void* __restrict__ b_out,
                          const void* __restrict__ in_a,  const void* __restrict__ out_a,
                          const void* __restrict__ w_ih,  const void* __restrict__ w_hh,
                          const void* __restrict__ b_ih,  const void* __restrict__ b_hh,
                          const void* __restrict__ w_fc,  const void* __restrict__ b_fc,
                          const void* __restrict__ item_emb, const void* __restrict__ resp_emb,
                          float* __restrict__ ws)
{
    const int isbf = ((const int*)(ws + DTFo))[0];
    const int tg  = blockIdx.x * blockDim.x + threadIdx.x;
    const int tot = gridDim.x * blockDim.x;
    for (int f = tg; f < 8192; f += tot) {
        int i = f & 63, j = f >> 6;
        ws[WINTo + f]  = ldg_any(w_in , i * 128 + j, isbf);
        ws[WOUTTo + f] = ldg_any(w_out, i * 128 + j, isbf);
    }
    for (int f = tg; f < 6144; f += tot) {
        int g = f % 96, j = f / 96;
        ws[WIHTo + f] = ldg_any(w_ih, g * 64 + j, isbf);
    }
    for (int f = tg; f < 3072; f += tot) ws[WHHo + f] = ldg_any(w_hh, f, isbf);
    for (int f = tg; f < 32;   f += tot) ws[WFCo + f] = ldg_any(w_fc, f, isbf);
    for (int f = tg; f < 64;   f += tot) { ws[BINo + f] = ldg_any(b_in, f, isbf); ws[BOUTo + f] = ldg_any(b_out, f, isbf); }
    for (int f = tg; f < 96;   f += tot) { ws[BIHo + f] = ldg_any(b_ih, f, isbf); ws[BHHo + f] = ldg_any(b_hh, f, isbf); }
    if (tg == 0) ws[BFCo] = ldg_any(b_fc, 0, isbf);
    for (int f = tg; f < 1024; f += tot) { ws[INAo + f] = ldg_any(in_a, f, isbf); ws[OUTAo + f] = ldg_any(out_a, f, isbf); }
    for (int f = tg; f < 32768; f += tot) ws[IEMo + f] = ldg_any(item_emb, f, isbf);
    for (int f = tg; f < 65536; f += tot) ws[REMo + f] = ldg_any(resp_emb, f, isbf);
}

// ---------------- prep: build CSC adjacency + quarter boundaries ----------------
__global__ void k_csc(const void* __restrict__ adj, float* __restrict__ ws)
{
    const int isbf = ((const int*)(ws + DTFo))[0];
    const int v = blockIdx.x;
    const int lane = threadIdx.x;
    int* ccnt = (int*)(ws + CCNTo);
    int* cidx = (int*)(ws + CIDXo);
    int* qcb  = (int*)(ws + QCNTo);
    int cnt = 0, c256 = 0, c512 = 0, c768 = 0;
    for (int ch = 0; ch < 16; ++ch) {
        int row = ch * 64 + lane;
        bool nz;
        if (isbf) nz = (((const unsigned short*)adj)[row * 1024 + v] != 0);
        else      nz = (((const float*)adj)[row * 1024 + v] != 0.f);
        unsigned long long m = __ballot(nz);
        int pos = cnt + __popcll(m & ((1ull << lane) - 1ull));
        if (nz && pos < CAP) cidx[v * CAP + pos] = row;
        cnt += __popcll(m);
        if (ch == 3)  c256 = cnt;
        if (ch == 7)  c512 = cnt;
        if (ch == 11) c768 = cnt;
    }
    if (lane == 0) {
        ccnt[v] = (cnt > CAP) ? CAP : cnt;
        qcb[v * 4 + 0] = (c256 > CAP) ? CAP : c256;
        qcb[v * 4 + 1] = (c512 > CAP) ? CAP : c512;
        qcb[v * 4 + 2] = (c768 > CAP) ? CAP : c768;
        qcb[v * 4 + 3] = 0;
    }
}

// ---------------- prep: out-neighbor bitmasks + static embedding sums ----------------
__global__ void k_emb(const void* __restrict__ adj, float* __restrict__ ws)
{
    const int isbf = ((const int*)(ws + DTFo))[0];
    const int v = blockIdx.x;
    const int lane = threadIdx.x;
    unsigned long long* om = (unsigned long long*)(ws + OMASKo);
    for (int w = 0; w < 16; ++w) {
        int col = w * 64 + lane;
        bool nz;
        if (isbf) nz = (((const unsigned short*)adj)[v * 1024 + col] != 0);
        else      nz = (((const float*)adj)[v * 1024 + col] != 0.f);
        unsigned long long m = __ballot(nz);
        if (lane == 0) om[v * 16 + w] = m;
    }
    const int cnt = ((const int*)(ws + CCNTo))[v];
    const int* cl = (const int*)(ws + CIDXo) + v * CAP;
    float acc = 0.f;
    for (int k = 0; k < cnt; ++k) {
        int u = cl[k];
        if (lane < 32) acc += ws[IEMo + u * 32 + lane];
    }
    if (lane < 32) ws[SUMEMBo + v * 32 + lane] = acc;
}

// ---------------- prep: zero barrier counters ----------------
__global__ void k_init(float* __restrict__ ws)
{
    if (threadIdx.x < 64) ((int*)(ws + BARo))[threadIdx.x] = 0;
}

// ---------------- main: 256 blocks = 4 per batch (cooperative) ----------------
// Block owns nodes [sub*256, sub*256+256): h + gi live in LDS for the whole kernel.
// Cross-block traffic per step = partial h-sums only (parity double-buffered, 1 bar4/step).
__global__ __launch_bounds__(512) void gkt_main(
    const int* __restrict__ item_ids, const int* __restrict__ responses,
    float* ws, float* __restrict__ out)
{
    extern __shared__ float smem[];
    float* h_lds = smem + LDSF_H;                         // [256][32]
    unsigned short* gi16 = (unsigned short*)(smem + LDSF_GI);  // [256][96] bf16
    float* fea_stage = smem + LDSF_FEA;                   // [8][192]
    int* dlist = (int*)(smem + LDSF_DL);                  // [128]

    const int tid  = threadIdx.x;
    const int lane = tid & 63;
    const int wave = tid >> 6;         // 0..7
    const int b    = blockIdx.x & 63;
    const int sub  = blockIdx.x >> 6;  // 0..3
    const int base = sub * 256;
    const int s    = lane & 31;
    const int gsel = (lane >> 5) & 1;

    int* barc = (int*)(ws + BARo) + b;
    const float* __restrict__ winT  = ws + WINTo;
    const float* __restrict__ woutT = ws + WOUTTo;
    const float* __restrict__ wihT  = ws + WIHTo;
    const float* __restrict__ whh   = ws + WHHo;
    const float* __restrict__ bin_f = ws + BINo;
    const float* __restrict__ bout_f= ws + BOUTo;
    const float* __restrict__ bih_f = ws + BIHo;
    const float* __restrict__ bhh_f = ws + BHHo;
    const float* __restrict__ ina_f = ws + INAo;
    const float* __restrict__ outa_f= ws + OUTAo;
    const float* __restrict__ iem   = ws + IEMo;
    const float* __restrict__ rem   = ws + REMo;
    const float* __restrict__ semb  = ws + SUMEMBo;
    const int* __restrict__ ccnt = (const int*)(ws + CCNTo);
    const int* __restrict__ cidx = (const int*)(ws + CIDXo);
    const int* __restrict__ qcb  = (const int*)(ws + QCNTo);
    const unsigned long long* __restrict__ omk = (const unsigned long long*)(ws + OMASKo);

    // init LDS: h = 0, gi = b_ih (bf16)
    for (int i = tid; i < 8192; i += 512) h_lds[i] = 0.f;
    for (int i = tid; i < 24576; i += 512) gi16[i] = f2bf(bih_f[i % 96]);

    // register-stationary GRU recurrent weights for this lane's state index s
    float wr[32], wz[32], wn[32];
    #pragma unroll
    for (int j = 0; j < 32; ++j) {
        wr[j] = whh[s * 32 + j];
        wz[j] = whh[(32 + s) * 32 + j];
        wn[j] = whh[(64 + s) * 32 + j];
    }
    const float bhr = bhh_f[s], bhz = bhh_f[32 + s], bhn = bhh_f[64 + s];
    const float wfcs = ws[WFCo + s];
    const float bfc  = ws[BFCo];
    __syncthreads();

    int ep = 0;
    const int gid = wave * 2 + gsel;   // 0..15, owns rows [gid*16, gid*16+16)

    for (int t = 0; t < T_; ++t) {
        const int item = item_ids[b * T_ + t];
        const int resp = responses[b * T_ + t];
        const int ndst = ccnt[item];
        if (tid < ndst) dlist[tid] = cidx[item * CAP + tid];
        __syncthreads();
        const float remv = (lane >= 32) ? rem[resp * 32 + (lane - 32)] : 0.f;

        float* Pbuf = ws + PARTo + ((size_t)(t & 1) * 64 + b) * 16384;   // [i][128]

        // ---- phase P: partial h-sums over own 256 rows, for every dst i ----
        for (int i = wave; i < ndst; i += 8) {
            const int v = dlist[i];
            const int k0 = (sub == 0) ? 0 : qcb[v * 4 + sub - 1];
            const int k1 = (sub == 3) ? ccnt[v] : qcb[v * 4 + sub];
            float acc = 0.f;
            for (int k = k0; k < k1; ++k) {
                const int ul = cidx[v * CAP + k] - base;
                if (lane < 32) acc += h_lds[ul * 32 + lane];
            }
            if (lane < 32) Pbuf[i * 128 + sub * 32 + lane] = acc;
        }
        bar4(barc, ep, tid);   // publish partials (the ONLY cross-block sync per step)

        // ---- phase A': FC + gi for dst nodes in OWN range ----
        float* fstage = fea_stage + wave * 192;
        for (int i = wave; i < ndst; i += 8) {
            const int v = dlist[i];
            if ((v >> 8) != sub) continue;           // wave-uniform skip
            const int vl = v & 255;
            float own, agg;
            if (lane < 32) {
                own = h_lds[vl * 32 + lane];
                const float* pp = Pbuf + i * 128;
                agg = pp[lane] + pp[32 + lane] + pp[64 + lane] + pp[96 + lane];
            } else {
                const int j = lane - 32;
                own = (v == item) ? remv : iem[v * 32 + j];
                const bool hasitem = (omk[item * 16 + (v >> 6)] >> (v & 63)) & 1ull;
                agg = semb[v * 32 + j] + (hasitem ? (remv - iem[item * 32 + j]) : 0.f);
            }
            fstage[lane]      = own;
            fstage[64 + lane] = agg;
            float ain = 0.f, aout = 0.f;
            const float4* f4p = (const float4*)fstage;
            #pragma unroll 8
            for (int c = 0; c < 32; ++c) {
                const float4 f = f4p[c];
                ain  += f.x * winT [(4*c+0)*64 + lane] + f.y * winT [(4*c+1)*64 + lane]
                      + f.z * winT [(4*c+2)*64 + lane] + f.w * winT [(4*c+3)*64 + lane];
                aout += f.x * woutT[(4*c+0)*64 + lane] + f.y * woutT[(4*c+1)*64 + lane]
                      + f.z * woutT[(4*c+2)*64 + lane] + f.w * woutT[(4*c+3)*64 + lane];
            }
            ain  += bin_f[lane];
            aout += bout_f[lane];
            const float dstv = outa_f[v] * aout + ina_f[v] * ain;
            fstage[128 + lane] = dstv;
            float g0 = bih_f[lane];
            float g1 = (lane < 32) ? bih_f[64 + lane] : 0.f;
            const float4* d4p = (const float4*)(fstage + 128);
            #pragma unroll 8
            for (int c = 0; c < 16; ++c) {
                const float4 dv = d4p[c];
                g0 += dv.x * wihT[(4*c+0)*96 + lane] + dv.y * wihT[(4*c+1)*96 + lane]
                    + dv.z * wihT[(4*c+2)*96 + lane] + dv.w * wihT[(4*c+3)*96 + lane];
                if (lane < 32) {
                    g1 += dv.x * wihT[(4*c+0)*96 + 64 + lane] + dv.y * wihT[(4*c+1)*96 + 64 + lane]
                        + dv.z * wihT[(4*c+2)*96 + 64 + lane] + dv.w * wihT[(4*c+3)*96 + 64 + lane];
                }
            }
            gi16[vl * 96 + lane] = f2bf(g0);
            if (lane < 32) gi16[vl * 96 + 64 + lane] = f2bf(g1);
        }
        __syncthreads();   // gi_lds visible to phase B

        // ---- phase B: GRU on own rows [gid*16, gid*16+16), all LDS ----
        {
            int nl = gid * 16;
            unsigned short cS = gi16[nl * 96 + s], c32 = gi16[nl * 96 + 32 + s], c64 = gi16[nl * 96 + 64 + s];
            const float4* hrow = (const float4*)(h_lds + nl * 32);
            float4 ch[8];
            #pragma unroll
            for (int q = 0; q < 8; ++q) ch[q] = hrow[q];
            float h_own = h_lds[nl * 32 + s];

            for (int i = 0; i < 16; ++i, ++nl) {
                unsigned short nS = 0, n32 = 0, n64 = 0;
                float4 nh[8];
                float nh_own = 0.f;
                if (i < 15) {
                    nS  = gi16[(nl + 1) * 96 + s];
                    n32 = gi16[(nl + 1) * 96 + 32 + s];
                    n64 = gi16[(nl + 1) * 96 + 64 + s];
                    const float4* hnx = (const float4*)(h_lds + (nl + 1) * 32);
                    #pragma unroll
                    for (int q = 0; q < 8; ++q) nh[q] = hnx[q];
                    nh_own = h_lds[(nl + 1) * 32 + s];
                }
                float ar = bhr, az = bhz, an = bhn;
                const float* hf = (const float*)ch;
                #pragma unroll
                for (int j = 0; j < 32; ++j) {
                    const float hv = hf[j];
                    ar += wr[j] * hv; az += wz[j] * hv; an += wn[j] * hv;
                }
                const float gir = bf2f(cS), giz = bf2f(c32), gin = bf2f(c64);
                const float rg = sigm(gir + ar);
                const float zg = sigm(giz + az);
                const float ng = tanhx(gin + rg * an);
                const float hv2 = (1.f - zg) * ng + zg * h_own;
                h_lds[nl * 32 + s] = hv2;
                float red = hv2 * wfcs;
                red += __shfl_xor(red, 16); red += __shfl_xor(red, 8);
                red += __shfl_xor(red, 4);  red += __shfl_xor(red, 2);
                red += __shfl_xor(red, 1);
                const int n = base + nl;
                if (s == 0) __builtin_nontemporal_store(sigm(red + bfc),
                                out + (size_t)b * 65536 + (size_t)t * 1024 + n);
                if (t == T_ - 1) __builtin_nontemporal_store(hv2,
                                out + OUT0 + (size_t)b * 32768 + (size_t)n * 32 + s);
                cS = nS; c32 = n32; c64 = n64; h_own = nh_own;
                #pragma unroll
                for (int q = 0; q < 8; ++q) ch[q] = nh[q];
            }
        }
        __syncthreads();   // h_lds writes visible to next step's phase P (block-local)
    }
}

extern "C" void kernel_launch(void* const* d_in, const int* in_sizes, int n_in,
                              void* d_out, int out_size, void* d_ws, size_t ws_size,
                              hipStream_t stream)
{
    (void)in_sizes; (void)n_in; (void)out_size; (void)ws_size;
    const int* item_ids  = (const int*)d_in[0];
    const int* responses = (const int*)d_in[1];
    const void* adj      = d_in[2];
    const void* item_emb = d_in[3];
    const void* resp_emb = d_in[4];
    const void* w_in  = d_in[5];
    const void* b_in  = d_in[6];
    const void* w_out = d_in[7];
    const void* b_out = d_in[8];
    const void* in_a  = d_in[9];
    const void* out_a = d_in[10];
    const void* w_ih  = d_in[11];
    const void* w_hh  = d_in[12];
    const void* b_ih  = d_in[13];
    const void* b_hh  = d_in[14];
    const void* w_fc  = d_in[15];
    const void* b_fc  = d_in[16];
    float* ws = (float*)d_ws;
    float* out = (float*)d_out;

    (void)hipFuncSetAttribute((const void*)gkt_main,
                              hipFuncAttributeMaxDynamicSharedMemorySize, LDS_BYTES);

    k_detect<<<dim3(1), dim3(1024), 0, stream>>>((const unsigned int*)adj, ws);
    k_convert<<<dim3(64), dim3(256), 0, stream>>>(w_in, b_in, w_out, b_out, in_a, out_a,
                                                  w_ih, w_hh, b_ih, b_hh, w_fc, b_fc,
                                                  item_emb, resp_emb, ws);
    k_csc<<<dim3(1024), dim3(64), 0, stream>>>(adj, ws);
    k_emb<<<dim3(1024), dim3(64), 0, stream>>>(adj, ws);
    k_init<<<dim3(1), dim3(64), 0, stream>>>(ws);

    void* kargs[] = { (void*)&item_ids, (void*)&responses, (void*)&ws, (void*)&out };
    (void)hipLaunchCooperativeKernel((const void*)gkt_main, dim3(256), dim3(512),
                                     kargs, LDS_BYTES, stream);
}

// Round 13
// 2738.288 us; speedup vs baseline: 2.4894x; 1.0772x over previous
//
#include <hip/hip_runtime.h>

// ---------------- problem constants ----------------
constexpr int N_ = 1024;   // ITEM_SIZE
constexpr int B_ = 64;     // BATCH
constexpr int T_ = 64;     // SEQ
constexpr int CAP = 128;   // max in-degree cap (mean ~33, max ~60)
constexpr size_t OUT0 = (size_t)B_ * T_ * N_;   // 4,194,304 f32 (outs), then B*N*S h (f32)

// ---------------- workspace layout (float offsets) — total ~9.7 MB ----------------
constexpr size_t WINTo  = 0;        // w_in^T  [j][i] 128*64 = 8192
constexpr size_t WOUTTo = 8192;     // w_out^T                 8192
constexpr size_t WIHTo  = 16384;    // w_ih^T  [j][g]  64*96 = 6144
constexpr size_t WHHo   = 22528;    // w_hh row-major          3072
constexpr size_t WFCo   = 25600;    // 32
constexpr size_t BINo   = 25632;    // 64
constexpr size_t BOUTo  = 25696;    // 64
constexpr size_t BIHo   = 25760;    // 96
constexpr size_t BHHo   = 25856;    // 96
constexpr size_t BFCo   = 25952;    // 16 (1 used)
constexpr size_t INAo   = 25968;    // 1024
constexpr size_t OUTAo  = 26992;    // 1024
constexpr size_t CCNTo  = 28016;    // 1024 int (in-degree per node)
constexpr size_t DTFo   = 29040;    // 16 (dtype flag int)
constexpr size_t IEMo   = 29056;    // item_emb f32 32768
constexpr size_t REMo   = 61824;    // resp_emb f32 65536
constexpr size_t SUMEMBo= 127360;   // sum of item_emb over in-neighbors: 1024*32
constexpr size_t QCNTo  = 160128;   // 1024*4 ints: counts of cidx[v] entries < 256/512/768
constexpr size_t OMASKo = 164224;   // u64[1024][16]: omask[v] bit j = adj[v][j]  (32768 f slots)
constexpr size_t CIDXo  = 196992;   // 1024*128 int (CSC col lists, ascending)
constexpr size_t PARTo  = 328064;   // partial h-sums f32 [par2][b64][i128][sub4*32+lane32] = 2,097,152
constexpr size_t BARo   = 2425216;  // 64 ints: per-batch epoch barrier counters
// end = 2,425,280 floats ≈ 9.7 MB

// ---------------- LDS layout (dynamic, float offsets) ----------------
constexpr int LDSF_H   = 0;         // h block-range [256][32] f32 = 8192
constexpr int LDSF_GI  = 8192;      // gi [256][96] bf16 = 24576 ushort = 12288 f-slots
constexpr int LDSF_FEA = 20480;     // fea_stage [8][192] f32 = 1536
constexpr int LDSF_DL  = 22016;     // dlist 128 ints
constexpr int LDS_FLOATS = 22144;
constexpr int LDS_BYTES  = LDS_FLOATS * 4;   // 88,576 B -> 1 block/CU

// ---------------- helpers ----------------
__device__ __forceinline__ float bf2f(unsigned short u) {
    union { unsigned int i; float f; } x; x.i = ((unsigned int)u) << 16; return x.f;
}
__device__ __forceinline__ unsigned short f2bf(float f) {
    union { float f; unsigned int u; } x; x.f = f;
    unsigned int u = x.u;
    return (unsigned short)((u + 0x7fffu + ((u >> 16) & 1u)) >> 16);  // RNE
}
__device__ __forceinline__ float sigm(float x) { return 1.f / (1.f + __expf(-x)); }
__device__ __forceinline__ float tanhx(float x) {
    x = fminf(15.f, fmaxf(-15.f, x));
    float e = __expf(2.f * x);
    return (e - 1.f) / (e + 1.f);
}
__device__ __forceinline__ float ldg_any(const void* p, int i, int isbf) {
    return isbf ? bf2f(((const unsigned short*)p)[i]) : ((const float*)p)[i];
}

// Coherent-point (sc-flagged) 4B accessors: per-address agent coherence, no cache
// maintenance. Visibility guaranteed once vmcnt retires (i.e., after __syncthreads).
__device__ __forceinline__ void cstore(float* p, float v) {
    __hip_atomic_store((unsigned int*)p, __float_as_uint(v),
                       __ATOMIC_RELAXED, __HIP_MEMORY_SCOPE_AGENT);
}
__device__ __forceinline__ float cload(const float* p) {
    return __uint_as_float(__hip_atomic_load((const unsigned int*)p,
                       __ATOMIC_RELAXED, __HIP_MEMORY_SCOPE_AGENT));
}

// 4-block per-batch epoch barrier.
// ROUND-13: fence-free. All cross-block payload (Pbuf) uses sc-flagged atomics, so
// no buffer_wbl2/inv is needed (rounds 8-12 paid a whole-L2 writeback+invalidate per
// block per step). Leading __syncthreads drains all waves' stores (vmcnt(0)) before
// tid0 publishes arrival; relaxed polls read the coherent point directly.
__device__ __forceinline__ void bar4(int* c, int& ep, int tid) {
    __syncthreads();
    if (tid == 0) {
        __hip_atomic_fetch_add(c, 1, __ATOMIC_RELAXED, __HIP_MEMORY_SCOPE_AGENT);
        const int target = 4 * (++ep);
        while (__hip_atomic_load(c, __ATOMIC_RELAXED, __HIP_MEMORY_SCOPE_AGENT) < target)
            __builtin_amdgcn_s_sleep(1);
    } else {
        ++ep;
    }
    __syncthreads();
}

// ---------------- prep: detect input float dtype from adj bit patterns ----------------
__global__ void k_detect(const unsigned int* __restrict__ adjw, float* __restrict__ ws)
{
    __shared__ int f;
    if (threadIdx.x == 0) f = 0;
    __syncthreads();
    int local = 0;
    for (int i = threadIdx.x; i < 524288; i += blockDim.x) {
        unsigned int w = adjw[i];
        if ((w & 0xFFFFu) == 0x3F80u) local = 1;
    }
    if (local) atomicOr(&f, 1);
    __syncthreads();
    if (threadIdx.x == 0) ((int*)(ws + DTFo))[0] = f;
}

// ---------------- prep: convert/pack weights -> f32 ----------------
__global__ void k_convert(const void* __restrict__ w_in,  const void* __restrict__ b_in,
                          const void* __restrict__ w_out, const void* __restrict__ b_out,
                          const void* __restrict__ in_a,  const void* __restrict__ out_a,
                          const void* __restrict__ w_ih,  const void* __restrict__ w_hh,
                          const void* __restrict__ b_ih,  const void* __restrict__ b_hh,
                          const void* __restrict__ w_fc,  const void* __restrict__ b_fc,
                          const void* __restrict__ item_emb, const void* __restrict__ resp_emb,
                          float* __restrict__ ws)
{
    const int isbf = ((const int*)(ws + DTFo))[0];
    const int tg  = blockIdx.x * blockDim.x + threadIdx.x;
    const int tot = gridDim.x * blockDim.x;
    for (int f = tg; f < 8192; f += tot) {
        int i = f & 63, j = f >> 6;
        ws[WINTo + f]  = ldg_any(w_in , i * 128 + j, isbf);
        ws[WOUTTo + f] = ldg_any(w_out, i * 128 + j, isbf);
    }
    for (int f = tg; f < 6144; f += tot) {
        int g = f % 96, j = f / 96;
        ws[WIHTo + f] = ldg_any(w_ih, g * 64 + j, isbf);
    }
    for (int f = tg; f < 3072; f += tot) ws[WHHo + f] = ldg_any(w_hh, f, isbf);
    for (int f = tg; f < 32;   f += tot) ws[WFCo + f] = ldg_any(w_fc, f, isbf);
    for (int f = tg; f < 64;   f += tot) { ws[BINo + f] = ldg_any(b_in, f, isbf); ws[BOUTo + f] = ldg_any(b_out, f, isbf); }
    for (int f = tg; f < 96;   f += tot) { ws[BIHo + f] = ldg_any(b_ih, f, isbf); ws[BHHo + f] = ldg_any(b_hh, f, isbf); }
    if (tg == 0) ws[BFCo] = ldg_any(b_fc, 0, isbf);
    for (int f = tg; f < 1024; f += tot) { ws[INAo + f] = ldg_any(in_a, f, isbf); ws[OUTAo + f] = ldg_any(out_a, f, isbf); }
    for (int f = tg; f < 32768; f += tot) ws[IEMo + f] = ldg_any(item_emb, f, isbf);
    for (int f = tg; f < 65536; f += tot) ws[REMo + f] = ldg_any(resp_emb, f, isbf);
}

// ---------------- prep: build CSC adjacency + quarter boundaries ----------------
__global__ void k_csc(const void* __restrict__ adj, float* __restrict__ ws)
{
    const int isbf = ((const int*)(ws + DTFo))[0];
    const int v = blockIdx.x;
    const int lane = threadIdx.x;
    int* ccnt = (int*)(ws + CCNTo);
    int* cidx = (int*)(ws + CIDXo);
    int* qcb  = (int*)(ws + QCNTo);
    int cnt = 0, c256 = 0, c512 = 0, c768 = 0;
    for (int ch = 0; ch < 16; ++ch) {
        int row = ch * 64 + lane;
        bool nz;
        if (isbf) nz = (((const unsigned short*)adj)[row * 1024 + v] != 0);
        else      nz = (((const float*)adj)[row * 1024 + v] != 0.f);
        unsigned long long m = __ballot(nz);
        int pos = cnt + __popcll(m & ((1ull << lane) - 1ull));
        if (nz && pos < CAP) cidx[v * CAP + pos] = row;
        cnt += __popcll(m);
        if (ch == 3)  c256 = cnt;
        if (ch == 7)  c512 = cnt;
        if (ch == 11) c768 = cnt;
    }
    if (lane == 0) {
        ccnt[v] = (cnt > CAP) ? CAP : cnt;
        qcb[v * 4 + 0] = (c256 > CAP) ? CAP : c256;
        qcb[v * 4 + 1] = (c512 > CAP) ? CAP : c512;
        qcb[v * 4 + 2] = (c768 > CAP) ? CAP : c768;
        qcb[v * 4 + 3] = 0;
    }
}

// ---------------- prep: out-neighbor bitmasks + static embedding sums ----------------
__global__ void k_emb(const void* __restrict__ adj, float* __restrict__ ws)
{
    const int isbf = ((const int*)(ws + DTFo))[0];
    const int v = blockIdx.x;
    const int lane = threadIdx.x;
    unsigned long long* om = (unsigned long long*)(ws + OMASKo);
    for (int w = 0; w < 16; ++w) {
        int col = w * 64 + lane;
        bool nz;
        if (isbf) nz = (((const unsigned short*)adj)[v * 1024 + col] != 0);
        else      nz = (((const float*)adj)[v * 1024 + col] != 0.f);
        unsigned long long m = __ballot(nz);
        if (lane == 0) om[v * 16 + w] = m;
    }
    const int cnt = ((const int*)(ws + CCNTo))[v];
    const int* cl = (const int*)(ws + CIDXo) + v * CAP;
    float acc = 0.f;
    for (int k = 0; k < cnt; ++k) {
        int u = cl[k];
        if (lane < 32) acc += ws[IEMo + u * 32 + lane];
    }
    if (lane < 32) ws[SUMEMBo + v * 32 + lane] = acc;
}

// ---------------- prep: zero barrier counters ----------------
__global__ void k_init(float* __restrict__ ws)
{
    if (threadIdx.x < 64) ((int*)(ws + BARo))[threadIdx.x] = 0;
}

// ---------------- main: 256 blocks = 4 per batch (cooperative) ----------------
// Block owns nodes [sub*256, sub*256+256): h + gi live in LDS for the whole kernel.
// Cross-block traffic per step = sc-coherent partial h-sums only (parity dbuf, 1 bar4/step).
__global__ __launch_bounds__(512) void gkt_main(
    const int* __restrict__ item_ids, const int* __restrict__ responses,
    float* ws, float* __restrict__ out)
{
    extern __shared__ float smem[];
    float* h_lds = smem + LDSF_H;                         // [256][32]
    unsigned short* gi16 = (unsigned short*)(smem + LDSF_GI);  // [256][96] bf16
    float* fea_stage = smem + LDSF_FEA;                   // [8][192]
    int* dlist = (int*)(smem + LDSF_DL);                  // [128]

    const int tid  = threadIdx.x;
    const int lane = tid & 63;
    const int wave = tid >> 6;         // 0..7
    const int b    = blockIdx.x & 63;
    const int sub  = blockIdx.x >> 6;  // 0..3
    const int base = sub * 256;
    const int s    = lane & 31;
    const int gsel = (lane >> 5) & 1;

    int* barc = (int*)(ws + BARo) + b;
    const float* __restrict__ winT  = ws + WINTo;
    const float* __restrict__ woutT = ws + WOUTTo;
    const float* __restrict__ wihT  = ws + WIHTo;
    const float* __restrict__ whh   = ws + WHHo;
    const float* __restrict__ bin_f = ws + BINo;
    const float* __restrict__ bout_f= ws + BOUTo;
    const float* __restrict__ bih_f = ws + BIHo;
    const float* __restrict__ bhh_f = ws + BHHo;
    const float* __restrict__ ina_f = ws + INAo;
    const float* __restrict__ outa_f= ws + OUTAo;
    const float* __restrict__ iem   = ws + IEMo;
    const float* __restrict__ rem   = ws + REMo;
    const float* __restrict__ semb  = ws + SUMEMBo;
    const int* __restrict__ ccnt = (const int*)(ws + CCNTo);
    const int* __restrict__ cidx = (const int*)(ws + CIDXo);
    const int* __restrict__ qcb  = (const int*)(ws + QCNTo);
    const unsigned long long* __restrict__ omk = (const unsigned long long*)(ws + OMASKo);

    // init LDS: h = 0, gi = b_ih (bf16)
    for (int i = tid; i < 8192; i += 512) h_lds[i] = 0.f;
    for (int i = tid; i < 24576; i += 512) gi16[i] = f2bf(bih_f[i % 96]);

    // register-stationary GRU recurrent weights for this lane's state index s
    float wr[32], wz[32], wn[32];
    #pragma unroll
    for (int j = 0; j < 32; ++j) {
        wr[j] = whh[s * 32 + j];
        wz[j] = whh[(32 + s) * 32 + j];
        wn[j] = whh[(64 + s) * 32 + j];
    }
    const float bhr = bhh_f[s], bhz = bhh_f[32 + s], bhn = bhh_f[64 + s];
    const float wfcs = ws[WFCo + s];
    const float bfc  = ws[BFCo];
    __syncthreads();

    int ep = 0;
    const int gid = wave * 2 + gsel;   // 0..15, owns rows [gid*16, gid*16+16)

    for (int t = 0; t < T_; ++t) {
        const int item = item_ids[b * T_ + t];
        const int resp = responses[b * T_ + t];
        const int ndst = ccnt[item];
        if (tid < ndst) dlist[tid] = cidx[item * CAP + tid];
        __syncthreads();
        const float remv = (lane >= 32) ? rem[resp * 32 + (lane - 32)] : 0.f;

        float* Pbuf = ws + PARTo + ((size_t)(t & 1) * 64 + b) * 16384;   // [i][128]

        // ---- phase P: partial h-sums over own 256 rows, for every dst i ----
        for (int i = wave; i < ndst; i += 8) {
            const int v = dlist[i];
            const int k0 = (sub == 0) ? 0 : qcb[v * 4 + sub - 1];
            const int k1 = (sub == 3) ? ccnt[v] : qcb[v * 4 + sub];
            float acc = 0.f;
            for (int k = k0; k < k1; ++k) {
                const int ul = cidx[v * CAP + k] - base;
                if (lane < 32) acc += h_lds[ul * 32 + lane];
            }
            if (lane < 32) cstore(Pbuf + i * 128 + sub * 32 + lane, acc);
        }
        bar4(barc, ep, tid);   // publish partials (the ONLY cross-block sync per step)

        // ---- phase A': FC + gi for dst nodes in OWN range ----
        float* fstage = fea_stage + wave * 192;
        for (int i = wave; i < ndst; i += 8) {
            const int v = dlist[i];
            if ((v >> 8) != sub) continue;           // wave-uniform skip
            const int vl = v & 255;
            float own, agg;
            if (lane < 32) {
                own = h_lds[vl * 32 + lane];
                const float* pp = Pbuf + i * 128;
                agg = cload(pp + lane) + cload(pp + 32 + lane)
                    + cload(pp + 64 + lane) + cload(pp + 96 + lane);
            } else {
                const int j = lane - 32;
                own = (v == item) ? remv : iem[v * 32 + j];
                const bool hasitem = (omk[item * 16 + (v >> 6)] >> (v & 63)) & 1ull;
                agg = semb[v * 32 + j] + (hasitem ? (remv - iem[item * 32 + j]) : 0.f);
            }
            fstage[lane]      = own;
            fstage[64 + lane] = agg;
            float ain = 0.f, aout = 0.f;
            const float4* f4p = (const float4*)fstage;
            #pragma unroll 8
            for (int c = 0; c < 32; ++c) {
                const float4 f = f4p[c];
                ain  += f.x * winT [(4*c+0)*64 + lane] + f.y * winT [(4*c+1)*64 + lane]
                      + f.z * winT [(4*c+2)*64 + lane] + f.w * winT [(4*c+3)*64 + lane];
                aout += f.x * woutT[(4*c+0)*64 + lane] + f.y * woutT[(4*c+1)*64 + lane]
                      + f.z * woutT[(4*c+2)*64 + lane] + f.w * woutT[(4*c+3)*64 + lane];
            }
            ain  += bin_f[lane];
            aout += bout_f[lane];
            const float dstv = outa_f[v] * aout + ina_f[v] * ain;
            fstage[128 + lane] = dstv;
            float g0 = bih_f[lane];
            float g1 = (lane < 32) ? bih_f[64 + lane] : 0.f;
            const float4* d4p = (const float4*)(fstage + 128);
            #pragma unroll 8
            for (int c = 0; c < 16; ++c) {
                const float4 dv = d4p[c];
                g0 += dv.x * wihT[(4*c+0)*96 + lane] + dv.y * wihT[(4*c+1)*96 + lane]
                    + dv.z * wihT[(4*c+2)*96 + lane] + dv.w * wihT[(4*c+3)*96 + lane];
                if (lane < 32) {
                    g1 += dv.x * wihT[(4*c+0)*96 + 64 + lane] + dv.y * wihT[(4*c+1)*96 + 64 + lane]
                        + dv.z * wihT[(4*c+2)*96 + 64 + lane] + dv.w * wihT[(4*c+3)*96 + 64 + lane];
                }
            }
            gi16[vl * 96 + lane] = f2bf(g0);
            if (lane < 32) gi16[vl * 96 + 64 + lane] = f2bf(g1);
        }
        __syncthreads();   // gi_lds visible to phase B

        // ---- phase B: GRU on own rows [gid*16, gid*16+16), all LDS ----
        {
            int nl = gid * 16;
            unsigned short cS = gi16[nl * 96 + s], c32 = gi16[nl * 96 + 32 + s], c64 = gi16[nl * 96 + 64 + s];
            const float4* hrow = (const float4*)(h_lds + nl * 32);
            float4 ch[8];
            #pragma unroll
            for (int q = 0; q < 8; ++q) ch[q] = hrow[q];
            float h_own = h_lds[nl * 32 + s];

            for (int i = 0; i < 16; ++i, ++nl) {
                unsigned short nS = 0, n32 = 0, n64 = 0;
                float4 nh[8];
                float nh_own = 0.f;
                if (i < 15) {
                    nS  = gi16[(nl + 1) * 96 + s];
                    n32 = gi16[(nl + 1) * 96 + 32 + s];
                    n64 = gi16[(nl + 1) * 96 + 64 + s];
                    const float4* hnx = (const float4*)(h_lds + (nl + 1) * 32);
                    #pragma unroll
                    for (int q = 0; q < 8; ++q) nh[q] = hnx[q];
                    nh_own = h_lds[(nl + 1) * 32 + s];
                }
                float ar = bhr, az = bhz, an = bhn;
                const float* hf = (const float*)ch;
                #pragma unroll
                for (int j = 0; j < 32; ++j) {
                    const float hv = hf[j];
                    ar += wr[j] * hv; az += wz[j] * hv; an += wn[j] * hv;
                }
                const float gir = bf2f(cS), giz = bf2f(c32), gin = bf2f(c64);
                const float rg = sigm(gir + ar);
                const float zg = sigm(giz + az);
                const float ng = tanhx(gin + rg * an);
                const float hv2 = (1.f - zg) * ng + zg * h_own;
                h_lds[nl * 32 + s] = hv2;
                float red = hv2 * wfcs;
                red += __shfl_xor(red, 16); red += __shfl_xor(red, 8);
                red += __shfl_xor(red, 4);  red += __shfl_xor(red, 2);
                red += __shfl_xor(red, 1);
                const int n = base + nl;
                if (s == 0) __builtin_nontemporal_store(sigm(red + bfc),
                                out + (size_t)b * 65536 + (size_t)t * 1024 + n);
                if (t == T_ - 1) __builtin_nontemporal_store(hv2,
                                out + OUT0 + (size_t)b * 32768 + (size_t)n * 32 + s);
                cS = nS; c32 = n32; c64 = n64; h_own = nh_own;
                #pragma unroll
                for (int q = 0; q < 8; ++q) ch[q] = nh[q];
            }
        }
        __syncthreads();   // h_lds writes visible to next step's phase P (block-local)
    }
}

extern "C" void kernel_launch(void* const* d_in, const int* in_sizes, int n_in,
                              void* d_out, int out_size, void* d_ws, size_t ws_size,
                              hipStream_t stream)
{
    (void)in_sizes; (void)n_in; (void)out_size; (void)ws_size;
    const int* item_ids  = (const int*)d_in[0];
    const int* responses = (const int*)d_in[1];
    const void* adj      = d_in[2];
    const void* item_emb = d_in[3];
    const void* resp_emb = d_in[4];
    const void* w_in  = d_in[5];
    const void* b_in  = d_in[6];
    const void* w_out = d_in[7];
    const void* b_out = d_in[8];
    const void* in_a  = d_in[9];
    const void* out_a = d_in[10];
    const void* w_ih  = d_in[11];
    const void* w_hh  = d_in[12];
    const void* b_ih  = d_in[13];
    const void* b_hh  = d_in[14];
    const void* w_fc  = d_in[15];
    const void* b_fc  = d_in[16];
    float* ws = (float*)d_ws;
    float* out = (float*)d_out;

    (void)hipFuncSetAttribute((const void*)gkt_main,
                              hipFuncAttributeMaxDynamicSharedMemorySize, LDS_BYTES);

    k_detect<<<dim3(1), dim3(1024), 0, stream>>>((const unsigned int*)adj, ws);
    k_convert<<<dim3(64), dim3(256), 0, stream>>>(w_in, b_in, w_out, b_out, in_a, out_a,
                                                  w_ih, w_hh, b_ih, b_hh, w_fc, b_fc,
                                                  item_emb, resp_emb, ws);
    k_csc<<<dim3(1024), dim3(64), 0, stream>>>(adj, ws);
    k_emb<<<dim3(1024), dim3(64), 0, stream>>>(adj, ws);
    k_init<<<dim3(1), dim3(64), 0, stream>>>(ws);

    void* kargs[] = { (void*)&item_ids, (void*)&responses, (void*)&ws, (void*)&out };
    (void)hipLaunchCooperativeKernel((const void*)gkt_main, dim3(256), dim3(512),
                                     kargs, LDS_BYTES, stream);
}